// Round 13
// baseline (38.469 us; speedup 1.0000x reference)
//
#include <hip/hip_runtime.h>

// FlowWarpConsistencyLoss: B=16, C=3, H=W=512, flow 2x128x128.
// Pass 1: grayscale pred_next -> ZERO-PADDED fp16 buffer (576x576/img), XCD-
//         aligned (XCD k writes images 2k,2k+1 its loss blocks consume).
// Pass 2: block = 64x64 tile (R13: was 64x32); stage 104x104 fp16 gray tile
//         (halo 16) + 18x24 flow window into LDS (25.1 KB -> 6 blocks/CU);
//         gathers hit LDS; rare out-of-tile -> exact clamped read of padded
//         buffer; per-block partial -> d_ws slot (NO global atomics).
// Pass 3: single-block reduce of 1024 partials -> out.
// R12->R13: cooperative single-dispatch ABANDONED (graph-capture dropped the
//         launch; out never written). 3-launch is the proven design. 64x64
//         tiles cut staged gray/px 3.25->2.64 and halve partials.

typedef _Float16 half8 __attribute__((ext_vector_type(8)));

constexpr int B  = 16;
constexpr int H  = 512;
constexpr int W  = 512;
constexpr int FH = 128;
constexpr int FW = 128;
constexpr int HW  = H * W;
constexpr int IMG = 3 * HW;
constexpr int FHW = FH * FW;
constexpr float EPS = 0.001f;

constexpr int P    = 32;            // zero padding on every side (pass-1 buffer)
constexpr int PW   = W + 2 * P;     // 576
constexpr int PH   = H + 2 * P;     // 576
constexpr int PIMG = PW * PH;       // halves per padded image
constexpr int PQ8  = PH * (PW / 8); // half8-chunks per padded image (41472)

constexpr int TX = 64, TY = 64;     // output tile per block
constexpr int TW = 104, TH = 104;   // staged tile: [t-16, t+88) both axes
constexpr int FROWS = 18;           // flow rows staged (64*127/511 = 15.9 -> 18)
constexpr int FCOLS = 24;           // flow cols staged (4-aligned window)

constexpr int NB  = 1024;           // loss blocks (16 images x 64 tiles)
constexpr int NPG = B * PQ8 / 256;  // 2592 pad_gray blocks (= 8 x 324)

// ---------------- pass 1: gray(next) into padded fp16 buffer ----------------
__global__ __launch_bounds__(256) void pad_gray_kernel(
    const float* __restrict__ nxt, _Float16* __restrict__ g)
{
    // XCD-aligned chunking: XCD k (= blockIdx%8) handles chunk-blocks
    // [324k, 324k+324) = images 2k, 2k+1 (162 blocks/image).
    const int j   = blockIdx.x;
    const int q   = (((j & 7) * (NPG / 8)) + (j >> 3)) * 256 + threadIdx.x;
    const int b   = q / PQ8;
    const int r   = q - b * PQ8;
    const int py  = r / (PW / 8);
    const int qx  = r - py * (PW / 8);
    const int y   = py - P;
    const int xs  = qx * 8 - P;
    half8 o = (half8)0;
    if ((unsigned)y < (unsigned)H && (unsigned)xs <= (unsigned)(W - 8)) {
        const float* __restrict__ nb = nxt + (long)b * IMG + y * W + xs;
        #pragma unroll
        for (int h = 0; h < 2; ++h) {
            const float4 rr = *(const float4*)(nb + 4 * h);
            const float4 gg = *(const float4*)(nb + HW + 4 * h);
            const float4 bl = *(const float4*)(nb + 2 * HW + 4 * h);
            o[4 * h + 0] = (_Float16)(0.299f * rr.x + 0.587f * gg.x + 0.114f * bl.x);
            o[4 * h + 1] = (_Float16)(0.299f * rr.y + 0.587f * gg.y + 0.114f * bl.y);
            o[4 * h + 2] = (_Float16)(0.299f * rr.z + 0.587f * gg.z + 0.114f * bl.z);
            o[4 * h + 3] = (_Float16)(0.299f * rr.w + 0.587f * gg.w + 0.114f * bl.w);
        }
    }
    *(half8*)(g + (long)b * PIMG + py * PW + qx * 8) = o;
}

// ---------------- pass 2: LDS-tiled warp + loss, partials out ----------------
__global__ __launch_bounds__(256) void loss_kernel(
    const float* __restrict__ prev, const _Float16* __restrict__ gpad,
    const float* __restrict__ flow, double* __restrict__ psum,
    unsigned int* __restrict__ pcnt)
{
    __shared__ __align__(16) _Float16 smh[TW * TH];           // 21.6 KB
    __shared__ __align__(16) float    smf[2 * FROWS * FCOLS]; // 3.4 KB

    // XCD-chunked: 8 XCDs x 128 contiguous blocks (= 2 images each).
    const int bid = ((blockIdx.x & 7) << 7) | (blockIdx.x >> 3);
    const int b   = bid >> 6;              // 64 tiles per image
    const int t   = bid & 63;
    const int tx  = t & 7;                 // 8 x-tiles (64 wide)
    const int ty  = t >> 3;                // 8 y-tiles (64 tall)
    const int x0t = tx * TX;
    const int y0t = ty * TY;

    const float fr = (float)(127.0 / 511.0);
    const int fy_lo = (int)((float)y0t * fr);
    const int c0    = min((int)((float)x0t * fr) & ~3, FW - FCOLS); // 4-aligned window

    const _Float16* __restrict__ gb = gpad + (long)b * PIMG;

    // ---- stage gray tile [y0t-16, y0t+88) x [x0t-16, x0t+88)
    {
        const _Float16* __restrict__ src = gb + (y0t - 16 + P) * PW + (x0t - 16 + P);
        for (int it = threadIdx.x; it < TH * (TW / 8); it += 256) {
            const int r = it / (TW / 8), c = it - r * (TW / 8);
            *(uint4*)(smh + r * TW + c * 8) = *(const uint4*)(src + r * PW + c * 8);
        }
        // ---- stage flow window: FROWS x FCOLS, u then v (216 float4, one shot)
        const float* __restrict__ fsrc = flow + (long)b * 2 * FHW;
        if (threadIdx.x < 2 * FROWS * (FCOLS / 4)) {
            const int comp = threadIdx.x / (FROWS * (FCOLS / 4));
            const int rem  = threadIdx.x - comp * (FROWS * (FCOLS / 4));
            const int rr   = rem / (FCOLS / 4);
            const int c4   = rem - rr * (FCOLS / 4);
            const int frow = min(fy_lo + rr, FH - 1);
            const float4 v = *(const float4*)(fsrc + comp * FHW + frow * FW + c0 + c4 * 4);
            *(float4*)(smf + comp * (FROWS * FCOLS) + rr * FCOLS + c4 * 4) = v;
        }
    }

    // ---- prev grayscale: thread = 4 consecutive x in rows yl+{0,16,32,48}
    const int xq = threadIdx.x & 15;
    const int yl = threadIdx.x >> 4;
    const int xb = x0t + xq * 4;

    float pg[4][4];
    #pragma unroll
    for (int k = 0; k < 4; ++k) {
        const int y = y0t + yl + k * 16;
        const float* __restrict__ pb = prev + (long)b * IMG + y * W + xb;
        const float4 pr  = *(const float4*)(pb);
        const float4 pgc = *(const float4*)(pb + HW);
        const float4 plc = *(const float4*)(pb + 2 * HW);
        pg[k][0] = 0.299f * pr.x + 0.587f * pgc.x + 0.114f * plc.x;
        pg[k][1] = 0.299f * pr.y + 0.587f * pgc.y + 0.114f * plc.y;
        pg[k][2] = 0.299f * pr.z + 0.587f * pgc.z + 0.114f * plc.z;
        pg[k][3] = 0.299f * pr.w + 0.587f * pgc.w + 0.114f * plc.w;
    }

    __syncthreads();

    const float sxfb = (float)xb * fr;
    const int F   = (int)sxfb;          // floor (x >= 0)
    const int Fl  = F - c0;             // local col of F (max 22 -> Fl+1 <= 23)
    const int F2l = min(F + 2, FW - 1) - c0;

    double lsum = 0.0;
    unsigned int lcnt = 0;

    #pragma unroll
    for (int k = 0; k < 4; ++k) {
        const int y = y0t + yl + k * 16;

        const float syf = (float)y * fr;
        const int   fy0 = (int)syf;
        const float wy  = syf - (float)fy0;
        const int r0 = fy0 - fy_lo;
        const int r1 = min(fy0 + 1, FH - 1) - fy_lo;

        const float* __restrict__ su = smf;
        const float* __restrict__ sv = smf + FROWS * FCOLS;
        const float u0a = su[r0 * FCOLS + Fl], u0b = su[r0 * FCOLS + Fl + 1], u0c = su[r0 * FCOLS + F2l];
        const float u1a = su[r1 * FCOLS + Fl], u1b = su[r1 * FCOLS + Fl + 1], u1c = su[r1 * FCOLS + F2l];
        const float v0a = sv[r0 * FCOLS + Fl], v0b = sv[r0 * FCOLS + Fl + 1], v0c = sv[r0 * FCOLS + F2l];
        const float v1a = sv[r1 * FCOLS + Fl], v1b = sv[r1 * FCOLS + Fl + 1], v1c = sv[r1 * FCOLS + F2l];

        #pragma unroll
        for (int i = 0; i < 4; ++i) {
            const int x = xb + i;
            const float sxf = (float)x * fr;
            const int   fx0 = (int)sxf;
            const float wx  = sxf - (float)fx0;
            const int   d   = fx0 - F;   // 0 or 1

            const float u00 = d ? u0b : u0a, u01 = d ? u0c : u0b;
            const float u10 = d ? u1b : u1a, u11 = d ? u1c : u1b;
            const float v00 = d ? v0b : v0a, v01 = d ? v0c : v0b;
            const float v10 = d ? v1b : v1a, v11 = d ? v1c : v1b;

            // row-lerp then col-lerp (reference op order), then *4 scale
            const float uc0 = u00 * (1.0f - wy) + u10 * wy;
            const float uc1 = u01 * (1.0f - wy) + u11 * wy;
            const float vc0 = v00 * (1.0f - wy) + v10 * wy;
            const float vc1 = v01 * (1.0f - wy) + v11 * wy;
            const float u = (uc0 * (1.0f - wx) + uc1 * wx) * 4.0f;
            const float v = (vc0 * (1.0f - wx) + vc1 * wx) * 4.0f;

            const float gx = (float)x + u;
            const float gy = (float)y + v;
            const float vm = ((gx >= 0.0f) & (gx <= (float)(W - 1)) &
                              (gy >= 0.0f) & (gy <= (float)(H - 1))) ? 1.0f : 0.0f;

            const float gxf = floorf(gx), gyf = floorf(gy);
            const float wwx = gx - gxf,  wwy = gy - gyf;
            const int ix0 = (int)gxf, iy0 = (int)gyf;

            const int cx = ix0 - (x0t - 16);
            const int ry = iy0 - (y0t - 16);
            float c00, c01, c10, c11;
            if ((unsigned)cx <= (unsigned)(TW - 2) && (unsigned)ry <= (unsigned)(TH - 2)) {
                const int la = ry * TW + cx;
                c00 = (float)smh[la];      c01 = (float)smh[la + 1];
                c10 = (float)smh[la + TW]; c11 = (float)smh[la + TW + 1];
            } else {
                // rare: clamp into padded buffer. Clamped coords land in the
                // zero pad exactly matching reference per-corner zeroing.
                const int iyc = min(max(iy0, -P), PH - P - 2);
                const int ixc = min(max(ix0, -P), PW - P - 2);
                const _Float16* __restrict__ gp = gb + (iyc + P) * PW + (ixc + P);
                c00 = (float)gp[0];  c01 = (float)gp[1];
                c10 = (float)gp[PW]; c11 = (float)gp[PW + 1];
            }

            const float warped = c00 * (1.0f - wwx) * (1.0f - wwy)
                               + c01 * wwx * (1.0f - wwy)
                               + c10 * (1.0f - wwx) * wwy
                               + c11 * wwx * wwy;
            const float diff = pg[k][i] - warped;
            const float l = sqrtf(diff * diff + EPS * EPS);
            lsum += (double)(l * vm);
            lcnt += (unsigned int)vm;
        }
    }

    // ---- wave64 + block reduce; ONE partial store per block ----
    #pragma unroll
    for (int off = 32; off > 0; off >>= 1) {
        lsum += __shfl_down(lsum, off);
        lcnt += __shfl_down(lcnt, off);
    }
    __shared__ double s_sum[4];
    __shared__ unsigned int s_cnt[4];
    const int wid = threadIdx.x >> 6, lane = threadIdx.x & 63;
    if (lane == 0) { s_sum[wid] = lsum; s_cnt[wid] = lcnt; }
    __syncthreads();
    if (threadIdx.x == 0) {
        psum[blockIdx.x] = s_sum[0] + s_sum[1] + s_sum[2] + s_sum[3];
        pcnt[blockIdx.x] = s_cnt[0] + s_cnt[1] + s_cnt[2] + s_cnt[3];
    }
}

// ---------------- pass 3: reduce partials ----------------
__global__ __launch_bounds__(256) void reduce_kernel(
    const double* __restrict__ psum, const unsigned int* __restrict__ pcnt,
    float* __restrict__ out)
{
    double s = 0.0;
    unsigned long long c = 0;
    for (int i = threadIdx.x; i < NB; i += 256) {
        s += psum[i];
        c += (unsigned long long)pcnt[i];
    }
    #pragma unroll
    for (int off = 32; off > 0; off >>= 1) {
        s += __shfl_down(s, off);
        c += __shfl_down(c, off);
    }
    __shared__ double ss[4];
    __shared__ unsigned long long sc[4];
    const int wid = threadIdx.x >> 6, lane = threadIdx.x & 63;
    if (lane == 0) { ss[wid] = s; sc[wid] = c; }
    __syncthreads();
    if (threadIdx.x == 0) {
        const double ts = ss[0] + ss[1] + ss[2] + ss[3];
        double tc = (double)(sc[0] + sc[1] + sc[2] + sc[3]);
        if (tc < 1.0) tc = 1.0;
        const float loss = (float)(ts / tc);
        out[0] = loss;
        out[1] = loss;
    }
}

extern "C" void kernel_launch(void* const* d_in, const int* in_sizes, int n_in,
                              void* d_out, int out_size, void* d_ws, size_t ws_size,
                              hipStream_t stream) {
    const float* prev = (const float*)d_in[0];
    const float* nxt  = (const float*)d_in[1];
    const float* flow = (const float*)d_in[2];
    float* out = (float*)d_out;

    // ws layout: [0, NB*8) f64 partial sums; [NB*8, NB*12) uint counts;
    //            [32768, ...) padded fp16 gray buffer (10.6 MB)
    double* psum = (double*)d_ws;
    unsigned int* pcnt = (unsigned int*)((char*)d_ws + NB * 8);
    _Float16* gbuf = (_Float16*)((char*)d_ws + 32768);

    pad_gray_kernel<<<dim3(NPG), dim3(256), 0, stream>>>(nxt, gbuf);
    loss_kernel<<<dim3(NB), dim3(256), 0, stream>>>(prev, gbuf, flow, psum, pcnt);
    reduce_kernel<<<dim3(1), dim3(256), 0, stream>>>(psum, pcnt, out);
}

// Round 14
// 35.874 us; speedup vs baseline: 1.0723x; 1.0723x over previous
//
#include <hip/hip_runtime.h>

// FlowWarpConsistencyLoss: B=16, C=3, H=W=512, flow 2x128x128.  FINAL (R11 cfg)
// Pass 1: grayscale pred_next -> ZERO-PADDED fp16 buffer (576x576/img), XCD-
//         aligned (XCD k writes images 2k,2k+1 its loss blocks consume).
// Pass 2: block = 64x32 tile; stage 104x64 fp16 gray tile (halo 16) + 10x24
//         flow col-window (f32) into LDS (15.4 KB -> 8 blocks/CU); gathers hit
//         LDS; rare out-of-tile -> exact clamped read of zero-padded buffer;
//         per-block partial -> d_ws slot (NO global atomics).
// Pass 3: single-block reduce of 2048 partials -> out.
// Design-space verdicts (measured): single-address f64 atomics +90us (R2-R4);
// fused staging +8us (R7); ticket reduce = cross-XCD stale partials (R8,R10);
// cooperative launch dropped by graph capture (R12); 64x64 tiles +3.5us (R13);
// 120x80/halo-24 tiles +2us (R6 vs R9). 64x32/halo-16 3-launch is the optimum.

typedef _Float16 half8 __attribute__((ext_vector_type(8)));

constexpr int B  = 16;
constexpr int H  = 512;
constexpr int W  = 512;
constexpr int FH = 128;
constexpr int FW = 128;
constexpr int HW  = H * W;
constexpr int IMG = 3 * HW;
constexpr int FHW = FH * FW;
constexpr float EPS = 0.001f;

constexpr int P    = 32;            // zero padding on every side (pass-1 buffer)
constexpr int PW   = W + 2 * P;     // 576
constexpr int PH   = H + 2 * P;     // 576
constexpr int PIMG = PW * PH;       // halves per padded image
constexpr int PQ8  = PH * (PW / 8); // half8-chunks per padded image (41472)

constexpr int TX = 64, TY = 32;     // output tile per block
constexpr int TW = 104, TH = 64;    // staged tile: x [x0t-16,x0t+88), y [y0t-16,y0t+48)
constexpr int FROWS = 10;           // flow rows staged
constexpr int FCOLS = 24;           // flow cols staged (4-aligned window)

constexpr int NB  = 2048;           // blocks in loss (16 images x 128 tiles)
constexpr int NPG = B * PQ8 / 256;  // 2592 pad_gray blocks (= 8 x 324)

// ---------------- pass 1: gray(next) into padded fp16 buffer ----------------
__global__ __launch_bounds__(256) void pad_gray_kernel(
    const float* __restrict__ nxt, _Float16* __restrict__ g)
{
    // XCD-aligned chunking: XCD k (= blockIdx%8) handles chunk-blocks
    // [324k, 324k+324) = images 2k, 2k+1 (162 blocks/image).
    const int j   = blockIdx.x;
    const int q   = (((j & 7) * (NPG / 8)) + (j >> 3)) * 256 + threadIdx.x;
    const int b   = q / PQ8;
    const int r   = q - b * PQ8;
    const int py  = r / (PW / 8);
    const int qx  = r - py * (PW / 8);
    const int y   = py - P;
    const int xs  = qx * 8 - P;
    half8 o = (half8)0;
    if ((unsigned)y < (unsigned)H && (unsigned)xs <= (unsigned)(W - 8)) {
        const float* __restrict__ nb = nxt + (long)b * IMG + y * W + xs;
        #pragma unroll
        for (int h = 0; h < 2; ++h) {
            const float4 rr = *(const float4*)(nb + 4 * h);
            const float4 gg = *(const float4*)(nb + HW + 4 * h);
            const float4 bl = *(const float4*)(nb + 2 * HW + 4 * h);
            o[4 * h + 0] = (_Float16)(0.299f * rr.x + 0.587f * gg.x + 0.114f * bl.x);
            o[4 * h + 1] = (_Float16)(0.299f * rr.y + 0.587f * gg.y + 0.114f * bl.y);
            o[4 * h + 2] = (_Float16)(0.299f * rr.z + 0.587f * gg.z + 0.114f * bl.z);
            o[4 * h + 3] = (_Float16)(0.299f * rr.w + 0.587f * gg.w + 0.114f * bl.w);
        }
    }
    *(half8*)(g + (long)b * PIMG + py * PW + qx * 8) = o;
}

// ---------------- pass 2: LDS-tiled warp + loss, partials out ----------------
__global__ __launch_bounds__(256) void loss_kernel(
    const float* __restrict__ prev, const _Float16* __restrict__ gpad,
    const float* __restrict__ flow, double* __restrict__ psum,
    unsigned int* __restrict__ pcnt)
{
    __shared__ __align__(16) _Float16 smh[TW * TH];           // 13.3 KB
    __shared__ __align__(16) float    smf[2 * FROWS * FCOLS]; // 1.9 KB

    // XCD-chunked: 8 XCDs x 256 contiguous blocks (= 2 images each).
    const int bid = ((blockIdx.x & 7) << 8) | (blockIdx.x >> 3);
    const int b   = bid >> 7;              // 128 tiles per image
    const int t   = bid & 127;
    const int tx  = t & 7;                 // 8 x-tiles (64 wide)
    const int ty  = t >> 3;                // 16 y-tiles (32 tall)
    const int x0t = tx * TX;
    const int y0t = ty * TY;

    const float fr = (float)(127.0 / 511.0);
    const int fy_lo = (int)((float)y0t * fr);
    const int c0    = min((int)((float)x0t * fr) & ~3, FW - FCOLS); // 4-aligned col window

    const _Float16* __restrict__ gb = gpad + (long)b * PIMG;

    // ---- stage gray tile from fp16 padded buffer (uint4 chunks)
    {
        // tile origin (x0t-16, y0t-16) -> padded coords (+P)
        const _Float16* __restrict__ src = gb + (y0t - 16 + P) * PW + (x0t - 16 + P);
        for (int it = threadIdx.x; it < TH * (TW / 8); it += 256) {
            const int r = it / (TW / 8), c = it - r * (TW / 8);
            *(uint4*)(smh + r * TW + c * 8) = *(const uint4*)(src + r * PW + c * 8);
        }
        // ---- stage flow window: FROWS x FCOLS, u then v
        const float* __restrict__ fsrc = flow + (long)b * 2 * FHW;
        for (int it = threadIdx.x; it < 2 * FROWS * (FCOLS / 4); it += 256) {
            const int comp = it / (FROWS * (FCOLS / 4));
            const int rem  = it - comp * (FROWS * (FCOLS / 4));
            const int rr   = rem / (FCOLS / 4);
            const int c4   = rem - rr * (FCOLS / 4);
            const int frow = min(fy_lo + rr, FH - 1);
            const float4 v = *(const float4*)(fsrc + comp * FHW + frow * FW + c0 + c4 * 4);
            *(float4*)(smf + comp * (FROWS * FCOLS) + rr * FCOLS + c4 * 4) = v;
        }
    }

    // ---- prev grayscale: thread = 4 consecutive x in rows yl and yl+16
    const int xq = threadIdx.x & 15;
    const int yl = threadIdx.x >> 4;
    const int xb = x0t + xq * 4;

    float pg[2][4];
    #pragma unroll
    for (int k = 0; k < 2; ++k) {
        const int y = y0t + yl + k * 16;
        const float* __restrict__ pb = prev + (long)b * IMG + y * W + xb;
        const float4 pr  = *(const float4*)(pb);
        const float4 pgc = *(const float4*)(pb + HW);
        const float4 plc = *(const float4*)(pb + 2 * HW);
        pg[k][0] = 0.299f * pr.x + 0.587f * pgc.x + 0.114f * plc.x;
        pg[k][1] = 0.299f * pr.y + 0.587f * pgc.y + 0.114f * plc.y;
        pg[k][2] = 0.299f * pr.z + 0.587f * pgc.z + 0.114f * plc.z;
        pg[k][3] = 0.299f * pr.w + 0.587f * pgc.w + 0.114f * plc.w;
    }

    __syncthreads();

    const float sxfb = (float)xb * fr;
    const int F   = (int)sxfb;          // floor (x >= 0)
    const int Fl  = F - c0;             // local col of F
    const int F2l = min(F + 2, FW - 1) - c0;

    double lsum = 0.0;
    unsigned int lcnt = 0;

    #pragma unroll
    for (int k = 0; k < 2; ++k) {
        const int y = y0t + yl + k * 16;

        const float syf = (float)y * fr;
        const int   fy0 = (int)syf;
        const float wy  = syf - (float)fy0;
        const int r0 = fy0 - fy_lo;
        const int r1 = min(fy0 + 1, FH - 1) - fy_lo;

        const float* __restrict__ su = smf;
        const float* __restrict__ sv = smf + FROWS * FCOLS;
        const float u0a = su[r0 * FCOLS + Fl], u0b = su[r0 * FCOLS + Fl + 1], u0c = su[r0 * FCOLS + F2l];
        const float u1a = su[r1 * FCOLS + Fl], u1b = su[r1 * FCOLS + Fl + 1], u1c = su[r1 * FCOLS + F2l];
        const float v0a = sv[r0 * FCOLS + Fl], v0b = sv[r0 * FCOLS + Fl + 1], v0c = sv[r0 * FCOLS + F2l];
        const float v1a = sv[r1 * FCOLS + Fl], v1b = sv[r1 * FCOLS + Fl + 1], v1c = sv[r1 * FCOLS + F2l];

        #pragma unroll
        for (int i = 0; i < 4; ++i) {
            const int x = xb + i;
            const float sxf = (float)x * fr;
            const int   fx0 = (int)sxf;
            const float wx  = sxf - (float)fx0;
            const int   d   = fx0 - F;   // 0 or 1

            const float u00 = d ? u0b : u0a, u01 = d ? u0c : u0b;
            const float u10 = d ? u1b : u1a, u11 = d ? u1c : u1b;
            const float v00 = d ? v0b : v0a, v01 = d ? v0c : v0b;
            const float v10 = d ? v1b : v1a, v11 = d ? v1c : v1b;

            // row-lerp then col-lerp (reference op order), then *4 scale
            const float uc0 = u00 * (1.0f - wy) + u10 * wy;
            const float uc1 = u01 * (1.0f - wy) + u11 * wy;
            const float vc0 = v00 * (1.0f - wy) + v10 * wy;
            const float vc1 = v01 * (1.0f - wy) + v11 * wy;
            const float u = (uc0 * (1.0f - wx) + uc1 * wx) * 4.0f;
            const float v = (vc0 * (1.0f - wx) + vc1 * wx) * 4.0f;

            const float gx = (float)x + u;
            const float gy = (float)y + v;
            const float vm = ((gx >= 0.0f) & (gx <= (float)(W - 1)) &
                              (gy >= 0.0f) & (gy <= (float)(H - 1))) ? 1.0f : 0.0f;

            const float gxf = floorf(gx), gyf = floorf(gy);
            const float wwx = gx - gxf,  wwy = gy - gyf;
            const int ix0 = (int)gxf, iy0 = (int)gyf;

            const int cx = ix0 - (x0t - 16);
            const int ry = iy0 - (y0t - 16);
            float c00, c01, c10, c11;
            if ((unsigned)cx <= (unsigned)(TW - 2) && (unsigned)ry <= (unsigned)(TH - 2)) {
                const int la = ry * TW + cx;
                c00 = (float)smh[la];      c01 = (float)smh[la + 1];
                c10 = (float)smh[la + TW]; c11 = (float)smh[la + TW + 1];
            } else {
                // rare: clamp into padded buffer. Clamped coords land in the
                // zero pad exactly matching reference per-corner zeroing.
                const int iyc = min(max(iy0, -P), PH - P - 2);
                const int ixc = min(max(ix0, -P), PW - P - 2);
                const _Float16* __restrict__ gp = gb + (iyc + P) * PW + (ixc + P);
                c00 = (float)gp[0];  c01 = (float)gp[1];
                c10 = (float)gp[PW]; c11 = (float)gp[PW + 1];
            }

            const float warped = c00 * (1.0f - wwx) * (1.0f - wwy)
                               + c01 * wwx * (1.0f - wwy)
                               + c10 * (1.0f - wwx) * wwy
                               + c11 * wwx * wwy;
            const float diff = pg[k][i] - warped;
            const float l = sqrtf(diff * diff + EPS * EPS);
            lsum += (double)(l * vm);
            lcnt += (unsigned int)vm;
        }
    }

    // ---- wave64 + block reduce; ONE partial store per block ----
    #pragma unroll
    for (int off = 32; off > 0; off >>= 1) {
        lsum += __shfl_down(lsum, off);
        lcnt += __shfl_down(lcnt, off);
    }
    __shared__ double s_sum[4];
    __shared__ unsigned int s_cnt[4];
    const int wid = threadIdx.x >> 6, lane = threadIdx.x & 63;
    if (lane == 0) { s_sum[wid] = lsum; s_cnt[wid] = lcnt; }
    __syncthreads();
    if (threadIdx.x == 0) {
        psum[blockIdx.x] = s_sum[0] + s_sum[1] + s_sum[2] + s_sum[3];
        pcnt[blockIdx.x] = s_cnt[0] + s_cnt[1] + s_cnt[2] + s_cnt[3];
    }
}

// ---------------- pass 3: reduce partials ----------------
__global__ __launch_bounds__(256) void reduce_kernel(
    const double* __restrict__ psum, const unsigned int* __restrict__ pcnt,
    float* __restrict__ out)
{
    double s = 0.0;
    unsigned long long c = 0;
    for (int i = threadIdx.x; i < NB; i += 256) {
        s += psum[i];
        c += (unsigned long long)pcnt[i];
    }
    #pragma unroll
    for (int off = 32; off > 0; off >>= 1) {
        s += __shfl_down(s, off);
        c += __shfl_down(c, off);
    }
    __shared__ double ss[4];
    __shared__ unsigned long long sc[4];
    const int wid = threadIdx.x >> 6, lane = threadIdx.x & 63;
    if (lane == 0) { ss[wid] = s; sc[wid] = c; }
    __syncthreads();
    if (threadIdx.x == 0) {
        const double ts = ss[0] + ss[1] + ss[2] + ss[3];
        double tc = (double)(sc[0] + sc[1] + sc[2] + sc[3]);
        if (tc < 1.0) tc = 1.0;
        const float loss = (float)(ts / tc);
        out[0] = loss;
        out[1] = loss;
    }
}

extern "C" void kernel_launch(void* const* d_in, const int* in_sizes, int n_in,
                              void* d_out, int out_size, void* d_ws, size_t ws_size,
                              hipStream_t stream) {
    const float* prev = (const float*)d_in[0];
    const float* nxt  = (const float*)d_in[1];
    const float* flow = (const float*)d_in[2];
    float* out = (float*)d_out;

    // ws layout: [0, NB*8) f64 partial sums; [NB*8, NB*12) uint counts;
    //            [32768, ...) padded fp16 gray buffer (10.6 MB)
    double* psum = (double*)d_ws;
    unsigned int* pcnt = (unsigned int*)((char*)d_ws + NB * 8);
    _Float16* gbuf = (_Float16*)((char*)d_ws + 32768);

    pad_gray_kernel<<<dim3(NPG), dim3(256), 0, stream>>>(nxt, gbuf);
    loss_kernel<<<dim3(NB), dim3(256), 0, stream>>>(prev, gbuf, flow, psum, pcnt);
    reduce_kernel<<<dim3(1), dim3(256), 0, stream>>>(psum, pcnt, out);
}